// Round 3
// baseline (1472.876 us; speedup 1.0000x reference)
//
#include <hip/hip_runtime.h>
#include <cstdint>
#include <cstddef>

#define JAX_PARTITIONABLE 1

namespace {

constexpr int Bsz = 16, Nn = 1024, Dd = 256, Kk = 16, Ss = 512;
constexpr uint32_t BN = (uint32_t)Bsz * Nn;                    // 16384
constexpr int ZQ_SIZE = Bsz * Nn * Dd;                          // 4194304
constexpr int PQ_OFF = ZQ_SIZE;
constexpr int PROB_OFF = ZQ_SIZE + 1;
constexpr int BNS = Bsz * Nn * Ss;                              // 8388608
constexpr int LP_OFF = PROB_OFF + BNS;

// workspace layout (float offsets)
constexpr int WS_CP = 0;                           // 256
constexpr int WS_B2 = 256;                         // K*S = 8192
constexpr int WS_WB2 = WS_B2 + Kk * Ss;            // B*S = 8192
constexpr int WS_WBOOKS = WS_WB2 + Bsz * Ss;       // B*S*D = 2097152
constexpr int WS_BBF = WS_WBOOKS + Bsz * Ss * Dd;  // books bf16: 2M shorts = 1M floats
constexpr int WS_BTF = WS_BBF + (Kk * Ss * Dd) / 2; // bookT bf16 [k][d][s]
constexpr int WS_SC = WS_BTF + (Kk * Dd * Ss) / 2;  // scores f32 chunk [bn][kk][s]
// base (without SC) ~4.21M floats ~ 16.9 MB; SC adds BN*KG*512*4 bytes.

typedef __attribute__((ext_vector_type(8))) short bf16x8;
typedef __attribute__((ext_vector_type(4))) short short4v;
typedef __attribute__((ext_vector_type(4))) float f32x4;

struct KP { uint32_t a, b; };

__host__ __device__ constexpr KP tf2x32(uint32_t k0, uint32_t k1,
                                        uint32_t x0, uint32_t x1) {
  uint32_t ks[3] = {k0, k1, k0 ^ k1 ^ 0x1BD11BDAu};
  const int rot[2][4] = {{13, 15, 26, 6}, {17, 29, 16, 24}};
  x0 += ks[0];
  x1 += ks[1];
#pragma unroll
  for (int i = 0; i < 5; ++i) {
#pragma unroll
    for (int j = 0; j < 4; ++j) {
      int r = rot[i & 1][j];
      x0 += x1;
      x1 = (x1 << r) | (x1 >> (32 - r));
      x1 ^= x0;
    }
    x0 += ks[(i + 1) % 3];
    x1 += ks[(i + 2) % 3] + (uint32_t)(i + 1);
  }
  return {x0, x1};
}

#if JAX_PARTITIONABLE
constexpr KP KG1 = tf2x32(0u, 42u, 0u, 0u);
constexpr KP KG2 = tf2x32(0u, 42u, 0u, 1u);
#else
constexpr KP KH0 = tf2x32(0u, 42u, 0u, 2u);
constexpr KP KH1 = tf2x32(0u, 42u, 1u, 3u);
constexpr KP KG1 = {KH0.a, KH1.a};
constexpr KP KG2 = {KH0.b, KH1.b};
#endif

__device__ __forceinline__ float jax_gumbel(KP key, uint32_t idx, uint32_t half) {
#if JAX_PARTITIONABLE
  (void)half;
  KP h = tf2x32(key.a, key.b, 0u, idx);
  uint32_t bits = h.a ^ h.b;
#else
  uint32_t lo = idx < half ? idx : idx - half;
  KP h = tf2x32(key.a, key.b, lo, lo + half);
  uint32_t bits = idx < half ? h.a : h.b;
#endif
  float u = __uint_as_float((bits >> 9) | 0x3F800000u) - 1.0f;
  return -__logf(-__logf(u + 1e-10f) + 1e-10f);
}

__device__ __forceinline__ float prec_q(const float* p) {
  return 0.5f / fmaxf(1.0f + expf(p[0]), 1e-10f);
}

__device__ __forceinline__ short f2bf(float x) {  // RNE f32->bf16
  uint32_t u = __float_as_uint(x);
  uint32_t r = (u + 0x7FFFu + ((u >> 16) & 1u)) >> 16;
  return (short)r;
}

// ---------------- K1: c_probs (B,K) + precision_q ----------------
__global__ void __launch_bounds__(256) cprobs_kernel(
    const float* __restrict__ c_logits, const float* __restrict__ lpq,
    const float* __restrict__ lpq_cls, float* __restrict__ ws,
    float* __restrict__ out) {
  __shared__ float sl[256];
  const int t = threadIdx.x;
  const float pqc = prec_q(lpq_cls);
  float g = jax_gumbel(KG1, (uint32_t)t, 128u);
  sl[t] = (c_logits[t] * pqc + g) * 2.0f;  // /TEMP, TEMP=0.5
  __syncthreads();
  const int b = t >> 4;
  float m = -3.0e38f;
  for (int j = 0; j < 16; ++j) m = fmaxf(m, sl[b * 16 + j]);
  float sum = 0.f;
  for (int j = 0; j < 16; ++j) sum += expf(sl[b * 16 + j] - m);
  ws[WS_CP + t] = expf(sl[t] - m) / sum;
  if (t == 0) out[PQ_OFF] = prec_q(lpq);
}

// ---------------- K2: b2 (K*S) ----------------
__global__ void __launch_bounds__(256) norms_kernel(
    const float* __restrict__ books, float* __restrict__ ws) {
  const int row = blockIdx.x * 4 + (threadIdx.x >> 6);
  const int lane = threadIdx.x & 63;
  float4 v = ((const float4*)(books + (size_t)row * Dd))[lane];
  float s = v.x * v.x + v.y * v.y + v.z * v.z + v.w * v.w;
#pragma unroll
  for (int d = 1; d < 64; d <<= 1) s += __shfl_xor(s, d);
  if (lane == 0) ws[WS_B2 + row] = s;
}

// ---------------- K3: books -> bf16 + transposed bf16 ----------------
__global__ void __launch_bounds__(256) prep_kernel(
    const float* __restrict__ books, float* __restrict__ ws) {
  __shared__ short tile[16 * 256];
  const int k = blockIdx.x >> 5;
  const int s0 = (blockIdx.x & 31) << 4;
  short* bbf = (short*)(ws + WS_BBF);
  short* btf = (short*)(ws + WS_BTF);
  const int t = threadIdx.x;
#pragma unroll
  for (int i = 0; i < 4; ++i) {
    int idx = t + 256 * i;  // 0..1023
    int r = idx >> 6, dq = idx & 63;
    float4 v = ((const float4*)books)[(size_t)(k * Ss + s0 + r) * 64 + dq];
    short4v h = {f2bf(v.x), f2bf(v.y), f2bf(v.z), f2bf(v.w)};
    *(short4v*)&bbf[(size_t)(k * Ss + s0 + r) * 256 + dq * 4] = h;
    *(short4v*)&tile[r * 256 + dq * 4] = h;
  }
  __syncthreads();
  const int d = t;  // 0..255
  short vals[16];
#pragma unroll
  for (int r = 0; r < 16; ++r) vals[r] = tile[r * 256 + d];
  bf16x8 lo, hi;
#pragma unroll
  for (int r = 0; r < 8; ++r) { lo[r] = vals[r]; hi[r] = vals[r + 8]; }
  size_t base = ((size_t)(k * 256 + d)) * 512 + s0;
  *(bf16x8*)&btf[base] = lo;
  *(bf16x8*)&btf[base + 8] = hi;
}

// ---------------- K4: wbooks (B,S,D) and wb2 (B,S) ----------------
__global__ void __launch_bounds__(256) wbooks_kernel(
    const float* __restrict__ books, float* __restrict__ ws) {
  const int bs = blockIdx.x;           // b*512 + s
  const int b = bs >> 9, s = bs & 511;
  const int d = threadIdx.x;
  const float* cp = ws + WS_CP + b * 16;
  float acc = 0.f;
#pragma unroll
  for (int k = 0; k < 16; ++k)
    acc = fmaf(cp[k], books[((size_t)(k * Ss + s)) * Dd + d], acc);
  ws[WS_WBOOKS + ((size_t)(b * Ss + s)) * Dd + d] = acc;
  if (d == 0) {
    float a2 = 0.f;
#pragma unroll
    for (int k = 0; k < 16; ++k) a2 = fmaf(cp[k], ws[WS_B2 + k * Ss + s], a2);
    ws[WS_WB2 + b * Ss + s] = a2;
  }
}

// ---------------- K5: logits -> prob, log_prob (z2 dropped: softmax-invariant) ----
__global__ void __launch_bounds__(256, 4) logits_kernel(
    const float* __restrict__ ze, const float* __restrict__ lpq,
    const float* __restrict__ ws, float* __restrict__ out) {
  __shared__ float ze_s[8 * 256];
  __shared__ float ls[8 * 512];
  const int b = blockIdx.x >> 7;
  const int n0 = (blockIdx.x & 127) << 3;
  const int t = threadIdx.x;
  const float pq = prec_q(lpq);

  {
    const float4* zin = (const float4*)(ze + (size_t)(b * Nn + n0) * Dd);
    float4* zo = (float4*)ze_s;
    zo[t] = zin[t];
    zo[t + 256] = zin[t + 256];
  }
  __syncthreads();

  float acc0[8], acc1[8];
#pragma unroll
  for (int r = 0; r < 8; ++r) { acc0[r] = 0.f; acc1[r] = 0.f; }
  const int s0 = t, s1 = t + 256;
  const float4* w4_0 = (const float4*)(ws + WS_WBOOKS + (size_t)(b * Ss + s0) * Dd);
  const float4* w4_1 = (const float4*)(ws + WS_WBOOKS + (size_t)(b * Ss + s1) * Dd);
  const float4* z4 = (const float4*)ze_s;
  for (int dq = 0; dq < 64; ++dq) {
    float4 u0 = w4_0[dq], u1 = w4_1[dq];
#pragma unroll
    for (int r = 0; r < 8; ++r) {
      float4 z = z4[r * 64 + dq];
      acc0[r] = fmaf(z.x, u0.x, fmaf(z.y, u0.y, fmaf(z.z, u0.z, fmaf(z.w, u0.w, acc0[r]))));
      acc1[r] = fmaf(z.x, u1.x, fmaf(z.y, u1.y, fmaf(z.z, u1.z, fmaf(z.w, u1.w, acc1[r]))));
    }
  }
  const float wb2v0 = ws[WS_WB2 + b * Ss + s0];
  const float wb2v1 = ws[WS_WB2 + b * Ss + s1];
#pragma unroll
  for (int r = 0; r < 8; ++r) {
    ls[r * 512 + s0] = pq * (2.f * acc0[r] - wb2v0);
    ls[r * 512 + s1] = pq * (2.f * acc1[r] - wb2v1);
  }
  __syncthreads();

  const int r = t >> 5, c = t & 31;
  float m = -3.0e38f;
#pragma unroll
  for (int j = 0; j < 16; ++j) m = fmaxf(m, ls[r * 512 + c + 32 * j]);
#pragma unroll
  for (int d = 1; d < 32; d <<= 1) m = fmaxf(m, __shfl_xor(m, d));
  float ev[16];
  float sum = 0.f;
#pragma unroll
  for (int j = 0; j < 16; ++j) {
    ev[j] = expf(ls[r * 512 + c + 32 * j] - m);
    sum += ev[j];
  }
#pragma unroll
  for (int d = 1; d < 32; d <<= 1) sum += __shfl_xor(sum, d);
  const float inv = 1.f / sum;
  const float lsum = logf(sum);
  const size_t obase = (size_t)(b * Nn + n0 + r) * Ss;
  float* pr = out + PROB_OFF + obase;
  float* lp = out + LP_OFF + obase;
#pragma unroll
  for (int j = 0; j < 16; ++j) {
    int s = c + 32 * j;
    pr[s] = ev[j] * inv;
    lp[s] = (ls[r * 512 + s] - m) - lsum;
  }
}

// ---------------- K6a: GEMM1 split — raw scores -> ws_sc ----------------
// sc[bn][kk][s] = (2*(ze.books[k]^T) - b2)*pq   (identical fp to fused path)
__global__ void __launch_bounds__(512, 4) gemm1s_kernel(
    const float* __restrict__ ze, const float* __restrict__ lpq,
    float* __restrict__ ws, int k0, int KG) {
  __shared__ short ze_s[32 * 264];
  const int b = blockIdx.x >> 5;
  const int n0 = (blockIdx.x & 31) << 5;
  const int t = threadIdx.x;
  const int w = t >> 6, lane = t & 63, c = lane & 15, q = lane >> 4;
  const float pq = prec_q(lpq);
  const short* bbf = (const short*)(ws + WS_BBF);
  const float* b2p = ws + WS_B2;
  float* sc = ws + WS_SC;

#pragma unroll
  for (int i = 0; i < 4; ++i) {
    int idx = t + 512 * i;  // 0..2047
    int r = idx >> 6, dq = idx & 63;
    float4 v = ((const float4*)ze)[(size_t)(b * Nn + n0 + r) * 64 + dq];
    short4v h = {f2bf(v.x), f2bf(v.y), f2bf(v.z), f2bf(v.w)};
    *(short4v*)&ze_s[r * 264 + dq * 4] = h;
  }
  __syncthreads();

  for (int kk = 0; kk < KG; ++kk) {
    const int k = k0 + kk;
    f32x4 acc1[2][4];
#pragma unroll
    for (int rt = 0; rt < 2; ++rt)
#pragma unroll
      for (int st = 0; st < 4; ++st) acc1[rt][st] = (f32x4)(0.f);
    for (int dstep = 0; dstep < 8; ++dstep) {
      bf16x8 a0 = *(const bf16x8*)&ze_s[(c) * 264 + dstep * 32 + q * 8];
      bf16x8 a1 = *(const bf16x8*)&ze_s[(16 + c) * 264 + dstep * 32 + q * 8];
#pragma unroll
      for (int st = 0; st < 4; ++st) {
        bf16x8 bB = *(const bf16x8*)&bbf[((size_t)(k * Ss + w * 64 + st * 16 + c)) * 256 +
                                         dstep * 32 + q * 8];
        acc1[0][st] = __builtin_amdgcn_mfma_f32_16x16x32_bf16(a0, bB, acc1[0][st], 0, 0, 0);
        acc1[1][st] = __builtin_amdgcn_mfma_f32_16x16x32_bf16(a1, bB, acc1[1][st], 0, 0, 0);
      }
    }
    float b2v[4];
#pragma unroll
    for (int st = 0; st < 4; ++st) b2v[st] = b2p[k * Ss + w * 64 + st * 16 + c];
#pragma unroll
    for (int rt = 0; rt < 2; ++rt)
#pragma unroll
      for (int st = 0; st < 4; ++st)
#pragma unroll
        for (int reg = 0; reg < 4; ++reg) {
          int row = n0 + rt * 16 + q * 4 + reg;
          sc[((size_t)(b * Nn + row) * KG + kk) * Ss + (w * 64 + st * 16 + c)] =
              (2.f * acc1[rt][st][reg] - b2v[st]) * pq;
        }
  }
}

// ---------------- K6b: gumbel + row-softmax + cp-scale -> enc (bf16, in place) ----
// One wave per (bn, kk) row of 512 scores. High occupancy: this carries the
// threefry VALU load (134M hashes) at 8 waves/SIMD.
__global__ void __launch_bounds__(256, 8) gumbel_kernel(
    float* __restrict__ ws, int k0, int kgshift) {
  const int t = threadIdx.x;
  const int row = blockIdx.x * 4 + (t >> 6);
  const int lane = t & 63;
  const int bn = row >> kgshift;
  const int kk = row & ((1 << kgshift) - 1);
  const int k = k0 + kk;
  const int b = bn >> 10;  // Nn = 1024
  const float cpv = ws[WS_CP + b * 16 + k];

  float* sp = ws + WS_SC + (size_t)row * Ss;
  f32x4 v0 = *(const f32x4*)(sp + lane * 4);
  f32x4 v1 = *(const f32x4*)(sp + 256 + lane * 4);

  const uint32_t gbase = ((uint32_t)bn * (uint32_t)Kk + (uint32_t)k) * (uint32_t)Ss;
  float v[8];
#pragma unroll
  for (int j = 0; j < 4; ++j) {
    v[j] = (v0[j] + jax_gumbel(KG2, gbase + (uint32_t)(lane * 4 + j), 0u)) * 2.f;
    v[4 + j] = (v1[j] + jax_gumbel(KG2, gbase + (uint32_t)(256 + lane * 4 + j), 0u)) * 2.f;
  }
  float M = v[0];
#pragma unroll
  for (int j = 1; j < 8; ++j) M = fmaxf(M, v[j]);
#pragma unroll
  for (int d = 1; d < 64; d <<= 1) M = fmaxf(M, __shfl_xor(M, d));
  float T = 0.f;
#pragma unroll
  for (int j = 0; j < 8; ++j) {
    v[j] = __expf(v[j] - M);
    T += v[j];
  }
#pragma unroll
  for (int d = 1; d < 64; d <<= 1) T += __shfl_xor(T, d);
  const float scale = cpv * __builtin_amdgcn_rcpf(T);

  short* ep = (short*)sp;  // in-place: loads above complete (data dep) before stores
  short4v e0 = {f2bf(v[0] * scale), f2bf(v[1] * scale), f2bf(v[2] * scale), f2bf(v[3] * scale)};
  short4v e1 = {f2bf(v[4] * scale), f2bf(v[5] * scale), f2bf(v[6] * scale), f2bf(v[7] * scale)};
  *(short4v*)(ep + lane * 4) = e0;
  *(short4v*)(ep + 256 + lane * 4) = e1;
}

// ---------------- K6c: GEMM2 split — zq (+)= enc . bookT[k0..k0+KG) ----------------
__global__ void __launch_bounds__(512, 4) gemm2s_kernel(
    const float* __restrict__ ws, float* __restrict__ out, int k0, int KG) {
  const int b = blockIdx.x >> 5;
  const int n0 = (blockIdx.x & 31) << 5;
  const int t = threadIdx.x;
  const int w = t >> 6, lane = t & 63, c = lane & 15, q = lane >> 4;
  const short* btf = (const short*)(ws + WS_BTF);
  const short* ep = (const short*)(ws + WS_SC);  // enc rows: stride 1024 shorts

  f32x4 acc2[2][2];
#pragma unroll
  for (int rt = 0; rt < 2; ++rt)
#pragma unroll
    for (int dt = 0; dt < 2; ++dt) acc2[rt][dt] = (f32x4)(0.f);

  for (int kk = 0; kk < KG; ++kk) {
    const int k = k0 + kk;
    const size_t ar0 = ((size_t)(b * Nn + n0 + c) * KG + kk) * 1024;
    const size_t ar1 = ((size_t)(b * Nn + n0 + 16 + c) * KG + kk) * 1024;
    for (int ss = 0; ss < 16; ++ss) {
      bf16x8 a0 = *(const bf16x8*)&ep[ar0 + ss * 32 + q * 8];
      bf16x8 a1 = *(const bf16x8*)&ep[ar1 + ss * 32 + q * 8];
#pragma unroll
      for (int dt = 0; dt < 2; ++dt) {
        bf16x8 bB = *(const bf16x8*)&btf[((size_t)(k * 256 + w * 32 + dt * 16 + c)) * 512 +
                                         ss * 32 + q * 8];
        acc2[0][dt] = __builtin_amdgcn_mfma_f32_16x16x32_bf16(a0, bB, acc2[0][dt], 0, 0, 0);
        acc2[1][dt] = __builtin_amdgcn_mfma_f32_16x16x32_bf16(a1, bB, acc2[1][dt], 0, 0, 0);
      }
    }
  }

#pragma unroll
  for (int rt = 0; rt < 2; ++rt)
#pragma unroll
    for (int dt = 0; dt < 2; ++dt)
#pragma unroll
      for (int reg = 0; reg < 4; ++reg) {
        int row = n0 + rt * 16 + q * 4 + reg;
        int d = w * 32 + dt * 16 + c;
        size_t o = (size_t)(b * Nn + row) * Dd + d;
        if (k0 == 0) out[o] = acc2[rt][dt][reg];
        else out[o] += acc2[rt][dt][reg];
      }
}

// ---------------- K6 fused fallback (ws too small for split) ----------------
__global__ void __launch_bounds__(512, 4) zq_kernel(
    const float* __restrict__ ze, const float* __restrict__ lpq,
    const float* __restrict__ ws, float* __restrict__ out) {
  __shared__ short ze_s[32 * 264];
  __shared__ short enc_s[32 * 520];
  __shared__ float2 redms[32][9];   // pad 8->9: breaks 4-way bank conflict on combine
  __shared__ float cpk[16];

  const int b = blockIdx.x >> 5;
  const int n0 = (blockIdx.x & 31) << 5;
  const int t = threadIdx.x;
  const int w = t >> 6, lane = t & 63, c = lane & 15, q = lane >> 4;
  const float pq = prec_q(lpq);
  const short* bbf = (const short*)(ws + WS_BBF);
  const short* btf = (const short*)(ws + WS_BTF);
  const float* b2p = ws + WS_B2;

  if (t < 16) cpk[t] = ws[WS_CP + b * 16 + t];
#pragma unroll
  for (int i = 0; i < 4; ++i) {
    int idx = t + 512 * i;
    int r = idx >> 6, dq = idx & 63;
    float4 v = ((const float4*)ze)[(size_t)(b * Nn + n0 + r) * 64 + dq];
    short4v h = {f2bf(v.x), f2bf(v.y), f2bf(v.z), f2bf(v.w)};
    *(short4v*)&ze_s[r * 264 + dq * 4] = h;
  }
  __syncthreads();

  f32x4 acc2[2][2];
#pragma unroll
  for (int rt = 0; rt < 2; ++rt)
#pragma unroll
    for (int dt = 0; dt < 2; ++dt) acc2[rt][dt] = (f32x4)(0.f);

  for (int k = 0; k < 16; ++k) {
    f32x4 acc1[2][4];
#pragma unroll
    for (int rt = 0; rt < 2; ++rt)
#pragma unroll
      for (int st = 0; st < 4; ++st) acc1[rt][st] = (f32x4)(0.f);
    for (int dstep = 0; dstep < 8; ++dstep) {
      bf16x8 a0 = *(const bf16x8*)&ze_s[(c) * 264 + dstep * 32 + q * 8];
      bf16x8 a1 = *(const bf16x8*)&ze_s[(16 + c) * 264 + dstep * 32 + q * 8];
#pragma unroll
      for (int st = 0; st < 4; ++st) {
        bf16x8 bB = *(const bf16x8*)&bbf[((size_t)(k * Ss + w * 64 + st * 16 + c)) * 256 +
                                         dstep * 32 + q * 8];
        acc1[0][st] = __builtin_amdgcn_mfma_f32_16x16x32_bf16(a0, bB, acc1[0][st], 0, 0, 0);
        acc1[1][st] = __builtin_amdgcn_mfma_f32_16x16x32_bf16(a1, bB, acc1[1][st], 0, 0, 0);
      }
    }

    float b2v[4];
#pragma unroll
    for (int st = 0; st < 4; ++st) b2v[st] = b2p[k * Ss + w * 64 + st * 16 + c];
    float mx[2][4], sm[2][4];
#pragma unroll
    for (int rt = 0; rt < 2; ++rt)
#pragma unroll
      for (int reg = 0; reg < 4; ++reg) mx[rt][reg] = -3.0e38f;
#pragma unroll
    for (int rt = 0; rt < 2; ++rt)
#pragma unroll
      for (int st = 0; st < 4; ++st)
#pragma unroll
        for (int reg = 0; reg < 4; ++reg) {
          int row = n0 + rt * 16 + q * 4 + reg;
          uint32_t gi = ((uint32_t)(b * Nn + row) * (uint32_t)Kk + (uint32_t)k) * (uint32_t)Ss +
                        (uint32_t)(w * 64 + st * 16 + c);
          float g = jax_gumbel(KG2, gi, 0u);
          float v = ((2.f * acc1[rt][st][reg] - b2v[st]) * pq + g) * 2.f;
          acc1[rt][st][reg] = v;
          mx[rt][reg] = fmaxf(mx[rt][reg], v);
        }
#pragma unroll
    for (int m = 1; m < 16; m <<= 1)
#pragma unroll
      for (int rt = 0; rt < 2; ++rt)
#pragma unroll
        for (int reg = 0; reg < 4; ++reg)
          mx[rt][reg] = fmaxf(mx[rt][reg], __shfl_xor(mx[rt][reg], m));
#pragma unroll
    for (int rt = 0; rt < 2; ++rt)
#pragma unroll
      for (int reg = 0; reg < 4; ++reg) sm[rt][reg] = 0.f;
#pragma unroll
    for (int rt = 0; rt < 2; ++rt)
#pragma unroll
      for (int st = 0; st < 4; ++st)
#pragma unroll
        for (int reg = 0; reg < 4; ++reg) {
          float e = __expf(acc1[rt][st][reg] - mx[rt][reg]);
          acc1[rt][st][reg] = e;
          sm[rt][reg] += e;
        }
#pragma unroll
    for (int m = 1; m < 16; m <<= 1)
#pragma unroll
      for (int rt = 0; rt < 2; ++rt)
#pragma unroll
        for (int reg = 0; reg < 4; ++reg) sm[rt][reg] += __shfl_xor(sm[rt][reg], m);
    if (c == 0) {
#pragma unroll
      for (int rt = 0; rt < 2; ++rt)
#pragma unroll
        for (int reg = 0; reg < 4; ++reg) {
          int rl = rt * 16 + q * 4 + reg;
          redms[rl][w] = make_float2(mx[rt][reg], sm[rt][reg]);
        }
    }
    __syncthreads();

    const float cpv = cpk[k];
#pragma unroll
    for (int rt = 0; rt < 2; ++rt)
#pragma unroll
      for (int reg = 0; reg < 4; ++reg) {
        int rl = rt * 16 + q * 4 + reg;
        float M = mx[rt][reg];
#pragma unroll
        for (int w2 = 0; w2 < 8; ++w2) M = fmaxf(M, redms[rl][w2].x);
        float T = 0.f;
#pragma unroll
        for (int w2 = 0; w2 < 8; ++w2)
          T = fmaf(redms[rl][w2].y, __expf(redms[rl][w2].x - M), T);
        float scale = cpv * __expf(mx[rt][reg] - M) * __builtin_amdgcn_rcpf(T);
#pragma unroll
        for (int st = 0; st < 4; ++st)
          enc_s[rl * 520 + w * 64 + st * 16 + c] = f2bf(acc1[rt][st][reg] * scale);
      }
    __syncthreads();

    for (int ss = 0; ss < 16; ++ss) {
      bf16x8 a0 = *(const bf16x8*)&enc_s[(c) * 520 + ss * 32 + q * 8];
      bf16x8 a1 = *(const bf16x8*)&enc_s[(16 + c) * 520 + ss * 32 + q * 8];
#pragma unroll
      for (int dt = 0; dt < 2; ++dt) {
        bf16x8 bB = *(const bf16x8*)&btf[((size_t)(k * 256 + w * 32 + dt * 16 + c)) * 512 +
                                         ss * 32 + q * 8];
        acc2[0][dt] = __builtin_amdgcn_mfma_f32_16x16x32_bf16(a0, bB, acc2[0][dt], 0, 0, 0);
        acc2[1][dt] = __builtin_amdgcn_mfma_f32_16x16x32_bf16(a1, bB, acc2[1][dt], 0, 0, 0);
      }
    }
  }

#pragma unroll
  for (int rt = 0; rt < 2; ++rt)
#pragma unroll
    for (int dt = 0; dt < 2; ++dt)
#pragma unroll
      for (int reg = 0; reg < 4; ++reg) {
        int row = n0 + rt * 16 + q * 4 + reg;
        int d = w * 32 + dt * 16 + c;
        out[(size_t)(b * Nn + row) * Dd + d] = acc2[rt][dt][reg];
      }
}

}  // namespace

extern "C" void kernel_launch(void* const* d_in, const int* in_sizes, int n_in,
                              void* d_out, int out_size, void* d_ws, size_t ws_size,
                              hipStream_t stream) {
  (void)in_sizes; (void)n_in; (void)out_size;
  const float* ze = (const float*)d_in[0];
  const float* c_logits = (const float*)d_in[1];
  const float* books = (const float*)d_in[2];
  const float* lpq = (const float*)d_in[3];
  const float* lpq_cls = (const float*)d_in[4];
  float* out = (float*)d_out;
  float* ws = (float*)d_ws;

  hipLaunchKernelGGL(cprobs_kernel, dim3(1), dim3(256), 0, stream,
                     c_logits, lpq, lpq_cls, ws, out);
  hipLaunchKernelGGL(norms_kernel, dim3(Kk * Ss / 4), dim3(256), 0, stream, books, ws);
  hipLaunchKernelGGL(prep_kernel, dim3(Kk * 32), dim3(256), 0, stream, books, ws);
  hipLaunchKernelGGL(wbooks_kernel, dim3(Bsz * Ss), dim3(256), 0, stream, books, ws);
  hipLaunchKernelGGL(logits_kernel, dim3(Bsz * (Nn / 8)), dim3(256), 0, stream,
                     ze, lpq, ws, out);

  // Pick the largest K-chunk whose score buffer fits the workspace.
  int KG = 0, kgshift = 0;
  const size_t base_bytes = (size_t)WS_SC * 4;
  const int cands[3] = {4, 2, 1};
  const int shifts[3] = {2, 1, 0};
  for (int i = 0; i < 3; ++i) {
    size_t need = base_bytes + (size_t)BN * cands[i] * Ss * 4;
    if (ws_size >= need) { KG = cands[i]; kgshift = shifts[i]; break; }
  }

  if (KG > 0) {
    const int rows_per_group = (int)BN * KG;  // (bn, kk) rows
    for (int k0 = 0; k0 < Kk; k0 += KG) {
      hipLaunchKernelGGL(gemm1s_kernel, dim3(Bsz * (Nn / 32)), dim3(512), 0, stream,
                         ze, lpq, ws, k0, KG);
      hipLaunchKernelGGL(gumbel_kernel, dim3(rows_per_group / 4), dim3(256), 0, stream,
                         ws, k0, kgshift);
      hipLaunchKernelGGL(gemm2s_kernel, dim3(Bsz * (Nn / 32)), dim3(512), 0, stream,
                         ws, out, k0, KG);
    }
  } else {
    hipLaunchKernelGGL(zq_kernel, dim3(Bsz * (Nn / 32)), dim3(512), 0, stream,
                       ze, lpq, ws, out);
  }
}

// Round 4
// 1313.768 us; speedup vs baseline: 1.1211x; 1.1211x over previous
//
#include <hip/hip_runtime.h>
#include <cstdint>
#include <cstddef>

#define JAX_PARTITIONABLE 1

namespace {

constexpr int Bsz = 16, Nn = 1024, Dd = 256, Kk = 16, Ss = 512;
constexpr uint32_t BN = (uint32_t)Bsz * Nn;                    // 16384
constexpr int ZQ_SIZE = Bsz * Nn * Dd;                          // 4194304
constexpr int PQ_OFF = ZQ_SIZE;
constexpr int PROB_OFF = ZQ_SIZE + 1;
constexpr int BNS = Bsz * Nn * Ss;                              // 8388608
constexpr int LP_OFF = PROB_OFF + BNS;

// workspace layout (float offsets)
constexpr int WS_CP = 0;                           // 256
constexpr int WS_B2 = 256;                         // K*S = 8192
constexpr int WS_WB2 = WS_B2 + Kk * Ss;            // B*S = 8192
constexpr int WS_WBOOKS = WS_WB2 + Bsz * Ss;       // B*S*D = 2097152
constexpr int WS_BBF = WS_WBOOKS + Bsz * Ss * Dd;  // books bf16: 2M shorts = 1M floats
constexpr int WS_BTF = WS_BBF + (Kk * Ss * Dd) / 2; // bookT bf16 [k][d][s]
// total ~4.2M floats ~ 16.9 MB

typedef __attribute__((ext_vector_type(8))) short bf16x8;
typedef __attribute__((ext_vector_type(4))) short short4v;
typedef __attribute__((ext_vector_type(4))) float f32x4;

struct KP { uint32_t a, b; };

__host__ __device__ constexpr KP tf2x32(uint32_t k0, uint32_t k1,
                                        uint32_t x0, uint32_t x1) {
  uint32_t ks[3] = {k0, k1, k0 ^ k1 ^ 0x1BD11BDAu};
  const int rot[2][4] = {{13, 15, 26, 6}, {17, 29, 16, 24}};
  x0 += ks[0];
  x1 += ks[1];
#pragma unroll
  for (int i = 0; i < 5; ++i) {
#pragma unroll
    for (int j = 0; j < 4; ++j) {
      int r = rot[i & 1][j];
      x0 += x1;
      x1 = (x1 << r) | (x1 >> (32 - r));
      x1 ^= x0;
    }
    x0 += ks[(i + 1) % 3];
    x1 += ks[(i + 2) % 3] + (uint32_t)(i + 1);
  }
  return {x0, x1};
}

#if JAX_PARTITIONABLE
constexpr KP KG1 = tf2x32(0u, 42u, 0u, 0u);
constexpr KP KG2 = tf2x32(0u, 42u, 0u, 1u);
#else
constexpr KP KH0 = tf2x32(0u, 42u, 0u, 2u);
constexpr KP KH1 = tf2x32(0u, 42u, 1u, 3u);
constexpr KP KG1 = {KH0.a, KH1.a};
constexpr KP KG2 = {KH0.b, KH1.b};
#endif

__device__ __forceinline__ float jax_gumbel(KP key, uint32_t idx, uint32_t half) {
#if JAX_PARTITIONABLE
  (void)half;
  KP h = tf2x32(key.a, key.b, 0u, idx);
  uint32_t bits = h.a ^ h.b;
#else
  uint32_t lo = idx < half ? idx : idx - half;
  KP h = tf2x32(key.a, key.b, lo, lo + half);
  uint32_t bits = idx < half ? h.a : h.b;
#endif
  float u = __uint_as_float((bits >> 9) | 0x3F800000u) - 1.0f;
  return -__logf(-__logf(u + 1e-10f) + 1e-10f);
}

__device__ __forceinline__ float prec_q(const float* p) {
  return 0.5f / fmaxf(1.0f + expf(p[0]), 1e-10f);
}

__device__ __forceinline__ short f2bf(float x) {  // RNE f32->bf16
  uint32_t u = __float_as_uint(x);
  uint32_t r = (u + 0x7FFFu + ((u >> 16) & 1u)) >> 16;
  return (short)r;
}

// ---------------- K1: c_probs (B,K) + precision_q ----------------
__global__ void __launch_bounds__(256) cprobs_kernel(
    const float* __restrict__ c_logits, const float* __restrict__ lpq,
    const float* __restrict__ lpq_cls, float* __restrict__ ws,
    float* __restrict__ out) {
  __shared__ float sl[256];
  const int t = threadIdx.x;
  const float pqc = prec_q(lpq_cls);
  float g = jax_gumbel(KG1, (uint32_t)t, 128u);
  sl[t] = (c_logits[t] * pqc + g) * 2.0f;  // /TEMP, TEMP=0.5
  __syncthreads();
  const int b = t >> 4;
  float m = -3.0e38f;
  for (int j = 0; j < 16; ++j) m = fmaxf(m, sl[b * 16 + j]);
  float sum = 0.f;
  for (int j = 0; j < 16; ++j) sum += expf(sl[b * 16 + j] - m);
  ws[WS_CP + t] = expf(sl[t] - m) / sum;
  if (t == 0) out[PQ_OFF] = prec_q(lpq);
}

// ---------------- K2: b2 (K*S) ----------------
__global__ void __launch_bounds__(256) norms_kernel(
    const float* __restrict__ books, float* __restrict__ ws) {
  const int row = blockIdx.x * 4 + (threadIdx.x >> 6);
  const int lane = threadIdx.x & 63;
  float4 v = ((const float4*)(books + (size_t)row * Dd))[lane];
  float s = v.x * v.x + v.y * v.y + v.z * v.z + v.w * v.w;
#pragma unroll
  for (int d = 1; d < 64; d <<= 1) s += __shfl_xor(s, d);
  if (lane == 0) ws[WS_B2 + row] = s;
}

// ---------------- K3: books -> bf16 + transposed bf16 ----------------
__global__ void __launch_bounds__(256) prep_kernel(
    const float* __restrict__ books, float* __restrict__ ws) {
  __shared__ short tile[16 * 256];
  const int k = blockIdx.x >> 5;
  const int s0 = (blockIdx.x & 31) << 4;
  short* bbf = (short*)(ws + WS_BBF);
  short* btf = (short*)(ws + WS_BTF);
  const int t = threadIdx.x;
#pragma unroll
  for (int i = 0; i < 4; ++i) {
    int idx = t + 256 * i;  // 0..1023
    int r = idx >> 6, dq = idx & 63;
    float4 v = ((const float4*)books)[(size_t)(k * Ss + s0 + r) * 64 + dq];
    short4v h = {f2bf(v.x), f2bf(v.y), f2bf(v.z), f2bf(v.w)};
    *(short4v*)&bbf[(size_t)(k * Ss + s0 + r) * 256 + dq * 4] = h;
    *(short4v*)&tile[r * 256 + dq * 4] = h;
  }
  __syncthreads();
  const int d = t;  // 0..255
  short vals[16];
#pragma unroll
  for (int r = 0; r < 16; ++r) vals[r] = tile[r * 256 + d];
  bf16x8 lo, hi;
#pragma unroll
  for (int r = 0; r < 8; ++r) { lo[r] = vals[r]; hi[r] = vals[r + 8]; }
  size_t base = ((size_t)(k * 256 + d)) * 512 + s0;
  *(bf16x8*)&btf[base] = lo;
  *(bf16x8*)&btf[base + 8] = hi;
}

// ---------------- K4: wbooks (B,S,D) and wb2 (B,S) ----------------
__global__ void __launch_bounds__(256) wbooks_kernel(
    const float* __restrict__ books, float* __restrict__ ws) {
  const int bs = blockIdx.x;           // b*512 + s
  const int b = bs >> 9, s = bs & 511;
  const int d = threadIdx.x;
  const float* cp = ws + WS_CP + b * 16;
  float acc = 0.f;
#pragma unroll
  for (int k = 0; k < 16; ++k)
    acc = fmaf(cp[k], books[((size_t)(k * Ss + s)) * Dd + d], acc);
  ws[WS_WBOOKS + ((size_t)(b * Ss + s)) * Dd + d] = acc;
  if (d == 0) {
    float a2 = 0.f;
#pragma unroll
    for (int k = 0; k < 16; ++k) a2 = fmaf(cp[k], ws[WS_B2 + k * Ss + s], a2);
    ws[WS_WB2 + b * Ss + s] = a2;
  }
}

// ---------------- K5: logits -> prob, log_prob (z2 dropped: softmax-invariant) ----
__global__ void __launch_bounds__(256, 4) logits_kernel(
    const float* __restrict__ ze, const float* __restrict__ lpq,
    const float* __restrict__ ws, float* __restrict__ out) {
  __shared__ float ze_s[8 * 256];
  __shared__ float ls[8 * 512];
  const int b = blockIdx.x >> 7;
  const int n0 = (blockIdx.x & 127) << 3;
  const int t = threadIdx.x;
  const float pq = prec_q(lpq);

  {
    const float4* zin = (const float4*)(ze + (size_t)(b * Nn + n0) * Dd);
    float4* zo = (float4*)ze_s;
    zo[t] = zin[t];
    zo[t + 256] = zin[t + 256];
  }
  __syncthreads();

  float acc0[8], acc1[8];
#pragma unroll
  for (int r = 0; r < 8; ++r) { acc0[r] = 0.f; acc1[r] = 0.f; }
  const int s0 = t, s1 = t + 256;
  const float4* w4_0 = (const float4*)(ws + WS_WBOOKS + (size_t)(b * Ss + s0) * Dd);
  const float4* w4_1 = (const float4*)(ws + WS_WBOOKS + (size_t)(b * Ss + s1) * Dd);
  const float4* z4 = (const float4*)ze_s;
  for (int dq = 0; dq < 64; ++dq) {
    float4 u0 = w4_0[dq], u1 = w4_1[dq];
#pragma unroll
    for (int r = 0; r < 8; ++r) {
      float4 z = z4[r * 64 + dq];
      acc0[r] = fmaf(z.x, u0.x, fmaf(z.y, u0.y, fmaf(z.z, u0.z, fmaf(z.w, u0.w, acc0[r]))));
      acc1[r] = fmaf(z.x, u1.x, fmaf(z.y, u1.y, fmaf(z.z, u1.z, fmaf(z.w, u1.w, acc1[r]))));
    }
  }
  const float wb2v0 = ws[WS_WB2 + b * Ss + s0];
  const float wb2v1 = ws[WS_WB2 + b * Ss + s1];
#pragma unroll
  for (int r = 0; r < 8; ++r) {
    ls[r * 512 + s0] = pq * (2.f * acc0[r] - wb2v0);
    ls[r * 512 + s1] = pq * (2.f * acc1[r] - wb2v1);
  }
  __syncthreads();

  const int r = t >> 5, c = t & 31;
  float m = -3.0e38f;
#pragma unroll
  for (int j = 0; j < 16; ++j) m = fmaxf(m, ls[r * 512 + c + 32 * j]);
#pragma unroll
  for (int d = 1; d < 32; d <<= 1) m = fmaxf(m, __shfl_xor(m, d));
  float ev[16];
  float sum = 0.f;
#pragma unroll
  for (int j = 0; j < 16; ++j) {
    ev[j] = expf(ls[r * 512 + c + 32 * j] - m);
    sum += ev[j];
  }
#pragma unroll
  for (int d = 1; d < 32; d <<= 1) sum += __shfl_xor(sum, d);
  const float inv = 1.f / sum;
  const float lsum = logf(sum);
  const size_t obase = (size_t)(b * Nn + n0 + r) * Ss;
  float* pr = out + PROB_OFF + obase;
  float* lp = out + LP_OFF + obase;
#pragma unroll
  for (int j = 0; j < 16; ++j) {
    int s = c + 32 * j;
    pr[s] = ev[j] * inv;
    lp[s] = (ls[r * 512 + s] - m) - lsum;
  }
}

// ---------------- K6: fused MFMA zq ----------------
// 16-row n-tile, 512 thr (8 waves), grid 1024. Wave w: GEMM1 cols s in
// [w*64, w*64+64), GEMM2 d in [w*32, w*32+32). C-layout: col=lane&15,
// row=(lane>>4)*4+reg; A-frag: m=lane&15, k=(lane>>4)*8+j.
// Occupancy design: halved row-tile halves accumulator state (~72-80 live
// unified regs); __launch_bounds__(512,6) caps at 85 -> 3 blocks/CU
// (24 waves = 6/SIMD, LDS 3x26.4KB = 79KB ok). Round-1's spill came from
// the 64-reg cap; 85 should fit. 2 barriers per k (round-2 structure),
// redms padded [16][9] to kill the 4-way combine-read conflict.
__global__ void __launch_bounds__(512, 6) zq_kernel(
    const float* __restrict__ ze, const float* __restrict__ lpq,
    const float* __restrict__ ws, float* __restrict__ out) {
  __shared__ short ze_s[16 * 264];   // bf16, row stride 264 (bank-balanced)
  __shared__ short enc_s[16 * 520];  // bf16, row stride 520
  __shared__ float2 redms[16][9];    // [row][wave] (max, sum), padded
  __shared__ float cpk[16];

  const int b = blockIdx.x >> 6;
  const int n0 = (blockIdx.x & 63) << 4;
  const int t = threadIdx.x;
  const int w = t >> 6, lane = t & 63, c = lane & 15, q = lane >> 4;
  const float pq = prec_q(lpq);
  const short* bbf = (const short*)(ws + WS_BBF);
  const short* btf = (const short*)(ws + WS_BTF);
  const float* b2p = ws + WS_B2;

  if (t < 16) cpk[t] = ws[WS_CP + b * 16 + t];
#pragma unroll
  for (int i = 0; i < 2; ++i) {
    int idx = t + 512 * i;  // 0..1023
    int r = idx >> 6, dq = idx & 63;
    float4 v = ((const float4*)ze)[(size_t)(b * Nn + n0 + r) * 64 + dq];
    short4v h = {f2bf(v.x), f2bf(v.y), f2bf(v.z), f2bf(v.w)};
    *(short4v*)&ze_s[r * 264 + dq * 4] = h;
  }
  __syncthreads();

  f32x4 acc2[2];
#pragma unroll
  for (int dt = 0; dt < 2; ++dt) acc2[dt] = (f32x4)(0.f);

  for (int k = 0; k < 16; ++k) {
    // ---- GEMM1: scores = ze . books[k]^T
    f32x4 acc1[4];
#pragma unroll
    for (int st = 0; st < 4; ++st) acc1[st] = (f32x4)(0.f);
    for (int dstep = 0; dstep < 8; ++dstep) {
      bf16x8 a0 = *(const bf16x8*)&ze_s[(c) * 264 + dstep * 32 + q * 8];
#pragma unroll
      for (int st = 0; st < 4; ++st) {
        bf16x8 bB = *(const bf16x8*)&bbf[((size_t)(k * Ss + w * 64 + st * 16 + c)) * 256 +
                                         dstep * 32 + q * 8];
        acc1[st] = __builtin_amdgcn_mfma_f32_16x16x32_bf16(a0, bB, acc1[st], 0, 0, 0);
      }
    }

    // ---- scores + gumbel in C-layout registers
    float mx[4], sm[4];
#pragma unroll
    for (int reg = 0; reg < 4; ++reg) mx[reg] = -3.0e38f;
#pragma unroll
    for (int st = 0; st < 4; ++st) {
      const float b2v = b2p[k * Ss + w * 64 + st * 16 + c];
#pragma unroll
      for (int reg = 0; reg < 4; ++reg) {
        int row = n0 + q * 4 + reg;
        uint32_t gi = ((uint32_t)(b * Nn + row) * (uint32_t)Kk + (uint32_t)k) * (uint32_t)Ss +
                      (uint32_t)(w * 64 + st * 16 + c);
        float g = jax_gumbel(KG2, gi, 0u);
        float v = ((2.f * acc1[st][reg] - b2v) * pq + g) * 2.f;
        acc1[st][reg] = v;
        mx[reg] = fmaxf(mx[reg], v);
      }
    }
#pragma unroll
    for (int m = 1; m < 16; m <<= 1)
#pragma unroll
      for (int reg = 0; reg < 4; ++reg)
        mx[reg] = fmaxf(mx[reg], __shfl_xor(mx[reg], m));
#pragma unroll
    for (int reg = 0; reg < 4; ++reg) sm[reg] = 0.f;
#pragma unroll
    for (int st = 0; st < 4; ++st)
#pragma unroll
      for (int reg = 0; reg < 4; ++reg) {
        float e = __expf(acc1[st][reg] - mx[reg]);
        acc1[st][reg] = e;
        sm[reg] += e;
      }
#pragma unroll
    for (int m = 1; m < 16; m <<= 1)
#pragma unroll
      for (int reg = 0; reg < 4; ++reg) sm[reg] += __shfl_xor(sm[reg], m);
    if (c == 0) {
#pragma unroll
      for (int reg = 0; reg < 4; ++reg)
        redms[q * 4 + reg][w] = make_float2(mx[reg], sm[reg]);
    }
    __syncthreads();  // barA: red array complete; also orders enc writes after
                      // all GEMM2(k-1) reads.

    // ---- distributed combine: every lane computes M,T for its own 4 rows,
    //      then writes normalized enc (bf16, A-layout source)
    const float cpv = cpk[k];
#pragma unroll
    for (int reg = 0; reg < 4; ++reg) {
      int rl = q * 4 + reg;
      float M = mx[reg];
#pragma unroll
      for (int w2 = 0; w2 < 8; ++w2) M = fmaxf(M, redms[rl][w2].x);
      float T = 0.f;
#pragma unroll
      for (int w2 = 0; w2 < 8; ++w2)
        T = fmaf(redms[rl][w2].y, __expf(redms[rl][w2].x - M), T);
      float scale = cpv * __expf(mx[reg] - M) * __builtin_amdgcn_rcpf(T);
#pragma unroll
      for (int st = 0; st < 4; ++st)
        enc_s[rl * 520 + w * 64 + st * 16 + c] = f2bf(acc1[st][reg] * scale);
    }
    __syncthreads();  // barB: enc complete for GEMM2

    // ---- GEMM2: zq += enc . bookT[k]   (no tail barrier: next k's red/enc
    //      writes are ordered behind barA(k+1)/barB(k+1))
    for (int ss = 0; ss < 16; ++ss) {
      bf16x8 a0 = *(const bf16x8*)&enc_s[(c) * 520 + ss * 32 + q * 8];
#pragma unroll
      for (int dt = 0; dt < 2; ++dt) {
        bf16x8 bB = *(const bf16x8*)&btf[((size_t)(k * 256 + w * 32 + dt * 16 + c)) * 512 +
                                         ss * 32 + q * 8];
        acc2[dt] = __builtin_amdgcn_mfma_f32_16x16x32_bf16(a0, bB, acc2[dt], 0, 0, 0);
      }
    }
  }

  // ---- epilogue: C-layout -> global zq
#pragma unroll
  for (int dt = 0; dt < 2; ++dt)
#pragma unroll
    for (int reg = 0; reg < 4; ++reg) {
      int row = n0 + q * 4 + reg;
      int d = w * 32 + dt * 16 + c;
      out[(size_t)(b * Nn + row) * Dd + d] = acc2[dt][reg];
    }
}

}  // namespace

extern "C" void kernel_launch(void* const* d_in, const int* in_sizes, int n_in,
                              void* d_out, int out_size, void* d_ws, size_t ws_size,
                              hipStream_t stream) {
  (void)in_sizes; (void)n_in; (void)out_size; (void)ws_size;
  const float* ze = (const float*)d_in[0];
  const float* c_logits = (const float*)d_in[1];
  const float* books = (const float*)d_in[2];
  const float* lpq = (const float*)d_in[3];
  const float* lpq_cls = (const float*)d_in[4];
  float* out = (float*)d_out;
  float* ws = (float*)d_ws;

  hipLaunchKernelGGL(cprobs_kernel, dim3(1), dim3(256), 0, stream,
                     c_logits, lpq, lpq_cls, ws, out);
  hipLaunchKernelGGL(norms_kernel, dim3(Kk * Ss / 4), dim3(256), 0, stream, books, ws);
  hipLaunchKernelGGL(prep_kernel, dim3(Kk * 32), dim3(256), 0, stream, books, ws);
  hipLaunchKernelGGL(wbooks_kernel, dim3(Bsz * Ss), dim3(256), 0, stream, books, ws);
  hipLaunchKernelGGL(logits_kernel, dim3(Bsz * (Nn / 8)), dim3(256), 0, stream,
                     ze, lpq, ws, out);
  hipLaunchKernelGGL(zq_kernel, dim3(Bsz * (Nn / 16)), dim3(512), 0, stream,
                     ze, lpq, ws, out);
}

// Round 5
// 724.167 us; speedup vs baseline: 2.0339x; 1.8142x over previous
//
#include <hip/hip_runtime.h>
#include <cstdint>
#include <cstddef>

#define JAX_PARTITIONABLE 1

namespace {

constexpr int Bsz = 16, Nn = 1024, Dd = 256, Kk = 16, Ss = 512;
constexpr uint32_t BN = (uint32_t)Bsz * Nn;                    // 16384
constexpr int ZQ_SIZE = Bsz * Nn * Dd;                          // 4194304
constexpr int PQ_OFF = ZQ_SIZE;
constexpr int PROB_OFF = ZQ_SIZE + 1;
constexpr int BNS = Bsz * Nn * Ss;                              // 8388608
constexpr int LP_OFF = PROB_OFF + BNS;

// workspace layout (float offsets)
constexpr int WS_CP = 0;                           // 256
constexpr int WS_B2 = 256;                         // K*S = 8192
constexpr int WS_WB2 = WS_B2 + Kk * Ss;            // B*S = 8192
constexpr int WS_WBF = WS_WB2 + Bsz * Ss;          // wbooks bf16 [b][s][d]: 2M shorts
                                                    // (first half of old f32 region)
constexpr int WS_BBF = WS_WBF + Bsz * Ss * Dd;     // books bf16 (offset keeps old map)
constexpr int WS_BTF = WS_BBF + (Kk * Ss * Dd) / 2; // bookT bf16 [k][d][s]
// total ~4.2M floats ~ 16.9 MB

typedef __attribute__((ext_vector_type(8))) short bf16x8;
typedef __attribute__((ext_vector_type(4))) short short4v;
typedef __attribute__((ext_vector_type(4))) float f32x4;

struct KP { uint32_t a, b; };

__host__ __device__ constexpr KP tf2x32(uint32_t k0, uint32_t k1,
                                        uint32_t x0, uint32_t x1) {
  uint32_t ks[3] = {k0, k1, k0 ^ k1 ^ 0x1BD11BDAu};
  const int rot[2][4] = {{13, 15, 26, 6}, {17, 29, 16, 24}};
  x0 += ks[0];
  x1 += ks[1];
#pragma unroll
  for (int i = 0; i < 5; ++i) {
#pragma unroll
    for (int j = 0; j < 4; ++j) {
      int r = rot[i & 1][j];
      x0 += x1;
      x1 = (x1 << r) | (x1 >> (32 - r));
      x1 ^= x0;
    }
    x0 += ks[(i + 1) % 3];
    x1 += ks[(i + 2) % 3] + (uint32_t)(i + 1);
  }
  return {x0, x1};
}

#if JAX_PARTITIONABLE
constexpr KP KG1 = tf2x32(0u, 42u, 0u, 0u);
constexpr KP KG2 = tf2x32(0u, 42u, 0u, 1u);
#else
constexpr KP KH0 = tf2x32(0u, 42u, 0u, 2u);
constexpr KP KH1 = tf2x32(0u, 42u, 1u, 3u);
constexpr KP KG1 = {KH0.a, KH1.a};
constexpr KP KG2 = {KH0.b, KH1.b};
#endif

__device__ __forceinline__ float jax_gumbel(KP key, uint32_t idx, uint32_t half) {
#if JAX_PARTITIONABLE
  (void)half;
  KP h = tf2x32(key.a, key.b, 0u, idx);
  uint32_t bits = h.a ^ h.b;
#else
  uint32_t lo = idx < half ? idx : idx - half;
  KP h = tf2x32(key.a, key.b, lo, lo + half);
  uint32_t bits = idx < half ? h.a : h.b;
#endif
  float u = __uint_as_float((bits >> 9) | 0x3F800000u) - 1.0f;
  return -__logf(-__logf(u + 1e-10f) + 1e-10f);
}

__device__ __forceinline__ float prec_q(const float* p) {
  return 0.5f / fmaxf(1.0f + expf(p[0]), 1e-10f);
}

__device__ __forceinline__ short f2bf(float x) {  // RNE f32->bf16
  uint32_t u = __float_as_uint(x);
  uint32_t r = (u + 0x7FFFu + ((u >> 16) & 1u)) >> 16;
  return (short)r;
}

// ---------------- K1: c_probs (B,K) + precision_q ----------------
__global__ void __launch_bounds__(256) cprobs_kernel(
    const float* __restrict__ c_logits, const float* __restrict__ lpq,
    const float* __restrict__ lpq_cls, float* __restrict__ ws,
    float* __restrict__ out) {
  __shared__ float sl[256];
  const int t = threadIdx.x;
  const float pqc = prec_q(lpq_cls);
  float g = jax_gumbel(KG1, (uint32_t)t, 128u);
  sl[t] = (c_logits[t] * pqc + g) * 2.0f;  // /TEMP, TEMP=0.5
  __syncthreads();
  const int b = t >> 4;
  float m = -3.0e38f;
  for (int j = 0; j < 16; ++j) m = fmaxf(m, sl[b * 16 + j]);
  float sum = 0.f;
  for (int j = 0; j < 16; ++j) sum += expf(sl[b * 16 + j] - m);
  ws[WS_CP + t] = expf(sl[t] - m) / sum;
  if (t == 0) out[PQ_OFF] = prec_q(lpq);
}

// ---------------- K2: b2 (K*S) ----------------
__global__ void __launch_bounds__(256) norms_kernel(
    const float* __restrict__ books, float* __restrict__ ws) {
  const int row = blockIdx.x * 4 + (threadIdx.x >> 6);
  const int lane = threadIdx.x & 63;
  float4 v = ((const float4*)(books + (size_t)row * Dd))[lane];
  float s = v.x * v.x + v.y * v.y + v.z * v.z + v.w * v.w;
#pragma unroll
  for (int d = 1; d < 64; d <<= 1) s += __shfl_xor(s, d);
  if (lane == 0) ws[WS_B2 + row] = s;
}

// ---------------- K3: books -> bf16 + transposed bf16 ----------------
__global__ void __launch_bounds__(256) prep_kernel(
    const float* __restrict__ books, float* __restrict__ ws) {
  __shared__ short tile[16 * 256];
  const int k = blockIdx.x >> 5;
  const int s0 = (blockIdx.x & 31) << 4;
  short* bbf = (short*)(ws + WS_BBF);
  short* btf = (short*)(ws + WS_BTF);
  const int t = threadIdx.x;
#pragma unroll
  for (int i = 0; i < 4; ++i) {
    int idx = t + 256 * i;  // 0..1023
    int r = idx >> 6, dq = idx & 63;
    float4 v = ((const float4*)books)[(size_t)(k * Ss + s0 + r) * 64 + dq];
    short4v h = {f2bf(v.x), f2bf(v.y), f2bf(v.z), f2bf(v.w)};
    *(short4v*)&bbf[(size_t)(k * Ss + s0 + r) * 256 + dq * 4] = h;
    *(short4v*)&tile[r * 256 + dq * 4] = h;
  }
  __syncthreads();
  const int d = t;  // 0..255
  short vals[16];
#pragma unroll
  for (int r = 0; r < 16; ++r) vals[r] = tile[r * 256 + d];
  bf16x8 lo, hi;
#pragma unroll
  for (int r = 0; r < 8; ++r) { lo[r] = vals[r]; hi[r] = vals[r + 8]; }
  size_t base = ((size_t)(k * 256 + d)) * 512 + s0;
  *(bf16x8*)&btf[base] = lo;
  *(bf16x8*)&btf[base + 8] = hi;
}

// ---------------- K4: wbooks bf16 (B,S,D) and wb2 (B,S) ----------------
__global__ void __launch_bounds__(256) wbooks_kernel(
    const float* __restrict__ books, float* __restrict__ ws) {
  const int bs = blockIdx.x;           // b*512 + s
  const int b = bs >> 9, s = bs & 511;
  const int d = threadIdx.x;
  const float* cp = ws + WS_CP + b * 16;
  float acc = 0.f;
#pragma unroll
  for (int k = 0; k < 16; ++k)
    acc = fmaf(cp[k], books[((size_t)(k * Ss + s)) * Dd + d], acc);
  short* wbf = (short*)(ws + WS_WBF);
  wbf[((size_t)(b * Ss + s)) * Dd + d] = f2bf(acc);
  if (d == 0) {
    float a2 = 0.f;
#pragma unroll
    for (int k = 0; k < 16; ++k) a2 = fmaf(cp[k], ws[WS_B2 + k * Ss + s], a2);
    ws[WS_WB2 + b * Ss + s] = a2;
  }
}

// ---------------- K5: MFMA logits -> prob, log_prob ----------------
// logits[n][s] = (2*(ze . wbooks[b]^T) - wb2)*pq  (z2 dropped: softmax-invariant;
// Σk cp_k·cross_k == ze·wbooks by linearity). GEMM1-shaped tile: 32 rows,
// 8 waves, wave w owns s in [w*64, w*64+64). C-layout: col=lane&15,
// row=(lane>>4)*4+reg. Cross-wave softmax via redms (round-2 pattern, once).
__global__ void __launch_bounds__(512, 4) mlogits_kernel(
    const float* __restrict__ ze, const float* __restrict__ lpq,
    const float* __restrict__ ws, float* __restrict__ out) {
  __shared__ short ze_s[32 * 264];
  __shared__ float2 redms[32][9];
  const int b = blockIdx.x >> 5;
  const int n0 = (blockIdx.x & 31) << 5;
  const int t = threadIdx.x;
  const int w = t >> 6, lane = t & 63, c = lane & 15, q = lane >> 4;
  const float pq = prec_q(lpq);
  const short* wbf = (const short*)(ws + WS_WBF);
  const float* wb2 = ws + WS_WB2;

#pragma unroll
  for (int i = 0; i < 4; ++i) {
    int idx = t + 512 * i;  // 0..2047
    int r = idx >> 6, dq = idx & 63;
    float4 v = ((const float4*)ze)[(size_t)(b * Nn + n0 + r) * 64 + dq];
    short4v h = {f2bf(v.x), f2bf(v.y), f2bf(v.z), f2bf(v.w)};
    *(short4v*)&ze_s[r * 264 + dq * 4] = h;
  }
  __syncthreads();

  f32x4 acc1[2][4];
#pragma unroll
  for (int rt = 0; rt < 2; ++rt)
#pragma unroll
    for (int st = 0; st < 4; ++st) acc1[rt][st] = (f32x4)(0.f);
  for (int dstep = 0; dstep < 8; ++dstep) {
    bf16x8 a0 = *(const bf16x8*)&ze_s[(c) * 264 + dstep * 32 + q * 8];
    bf16x8 a1 = *(const bf16x8*)&ze_s[(16 + c) * 264 + dstep * 32 + q * 8];
#pragma unroll
    for (int st = 0; st < 4; ++st) {
      bf16x8 bB = *(const bf16x8*)&wbf[((size_t)(b * Ss + w * 64 + st * 16 + c)) * 256 +
                                       dstep * 32 + q * 8];
      acc1[0][st] = __builtin_amdgcn_mfma_f32_16x16x32_bf16(a0, bB, acc1[0][st], 0, 0, 0);
      acc1[1][st] = __builtin_amdgcn_mfma_f32_16x16x32_bf16(a1, bB, acc1[1][st], 0, 0, 0);
    }
  }

  // raw logits in C-layout registers + per-wave row max/sum
  float mx[2][4], sm[2][4];
#pragma unroll
  for (int rt = 0; rt < 2; ++rt)
#pragma unroll
    for (int reg = 0; reg < 4; ++reg) mx[rt][reg] = -3.0e38f;
#pragma unroll
  for (int st = 0; st < 4; ++st) {
    const float wb2v = wb2[b * Ss + w * 64 + st * 16 + c];
#pragma unroll
    for (int rt = 0; rt < 2; ++rt)
#pragma unroll
      for (int reg = 0; reg < 4; ++reg) {
        float v = (2.f * acc1[rt][st][reg] - wb2v) * pq;
        acc1[rt][st][reg] = v;
        mx[rt][reg] = fmaxf(mx[rt][reg], v);
      }
  }
#pragma unroll
  for (int m = 1; m < 16; m <<= 1)
#pragma unroll
    for (int rt = 0; rt < 2; ++rt)
#pragma unroll
      for (int reg = 0; reg < 4; ++reg)
        mx[rt][reg] = fmaxf(mx[rt][reg], __shfl_xor(mx[rt][reg], m));
#pragma unroll
  for (int rt = 0; rt < 2; ++rt)
#pragma unroll
    for (int reg = 0; reg < 4; ++reg) sm[rt][reg] = 0.f;
#pragma unroll
  for (int st = 0; st < 4; ++st)
#pragma unroll
    for (int rt = 0; rt < 2; ++rt)
#pragma unroll
      for (int reg = 0; reg < 4; ++reg)
        sm[rt][reg] += __expf(acc1[rt][st][reg] - mx[rt][reg]);
#pragma unroll
  for (int m = 1; m < 16; m <<= 1)
#pragma unroll
    for (int rt = 0; rt < 2; ++rt)
#pragma unroll
      for (int reg = 0; reg < 4; ++reg) sm[rt][reg] += __shfl_xor(sm[rt][reg], m);
  if (c == 0) {
#pragma unroll
    for (int rt = 0; rt < 2; ++rt)
#pragma unroll
      for (int reg = 0; reg < 4; ++reg)
        redms[rt * 16 + q * 4 + reg][w] = make_float2(mx[rt][reg], sm[rt][reg]);
  }
  __syncthreads();

  // distributed combine + write prob/log_prob
#pragma unroll
  for (int rt = 0; rt < 2; ++rt)
#pragma unroll
    for (int reg = 0; reg < 4; ++reg) {
      int rl = rt * 16 + q * 4 + reg;
      float M = mx[rt][reg];
#pragma unroll
      for (int w2 = 0; w2 < 8; ++w2) M = fmaxf(M, redms[rl][w2].x);
      float T = 0.f;
#pragma unroll
      for (int w2 = 0; w2 < 8; ++w2)
        T = fmaf(redms[rl][w2].y, __expf(redms[rl][w2].x - M), T);
      const float invT = __builtin_amdgcn_rcpf(T);
      const float lT = __logf(T);
      const size_t base = (size_t)(b * Nn + n0 + rl) * Ss;
#pragma unroll
      for (int st = 0; st < 4; ++st) {
        int s = w * 64 + st * 16 + c;
        float v = acc1[rt][st][reg] - M;
        out[PROB_OFF + base + s] = __expf(v) * invT;
        out[LP_OFF + base + s] = v - lT;
      }
    }
}

// ---------------- K6: fused MFMA zq (round-2 verified structure) ----------------
// 32-row n-tile, 512 thr (8 waves), grid 512. VGPR 64 + AGPR 48 = 112 unified
// -> 4 waves/SIMD band; do NOT cap tighter (rounds 1 & 4 proved it spills).
// 2 barriers/k; distributed combine; redms padded [32][9] (breaks the 4-way
// bank conflict on the combine reads: stride 18 floats -> banks {0,8,16,24}).
__global__ void __launch_bounds__(512, 4) zq_kernel(
    const float* __restrict__ ze, const float* __restrict__ lpq,
    const float* __restrict__ ws, float* __restrict__ out) {
  __shared__ short ze_s[32 * 264];   // bf16, row stride 264 (bank-balanced)
  __shared__ short enc_s[32 * 520];  // bf16, row stride 520
  __shared__ float2 redms[32][9];    // [row][wave] = (max, sum), padded
  __shared__ float cpk[16];

  const int b = blockIdx.x >> 5;
  const int n0 = (blockIdx.x & 31) << 5;
  const int t = threadIdx.x;
  const int w = t >> 6, lane = t & 63, c = lane & 15, q = lane >> 4;
  const float pq = prec_q(lpq);
  const short* bbf = (const short*)(ws + WS_BBF);
  const short* btf = (const short*)(ws + WS_BTF);
  const float* b2p = ws + WS_B2;

  if (t < 16) cpk[t] = ws[WS_CP + b * 16 + t];
#pragma unroll
  for (int i = 0; i < 4; ++i) {
    int idx = t + 512 * i;  // 0..2047
    int r = idx >> 6, dq = idx & 63;
    float4 v = ((const float4*)ze)[(size_t)(b * Nn + n0 + r) * 64 + dq];
    short4v h = {f2bf(v.x), f2bf(v.y), f2bf(v.z), f2bf(v.w)};
    *(short4v*)&ze_s[r * 264 + dq * 4] = h;
  }
  __syncthreads();

  f32x4 acc2[2][2];
#pragma unroll
  for (int rt = 0; rt < 2; ++rt)
#pragma unroll
    for (int dt = 0; dt < 2; ++dt) acc2[rt][dt] = (f32x4)(0.f);

  for (int k = 0; k < 16; ++k) {
    // ---- GEMM1: scores = ze . books[k]^T
    f32x4 acc1[2][4];
#pragma unroll
    for (int rt = 0; rt < 2; ++rt)
#pragma unroll
      for (int st = 0; st < 4; ++st) acc1[rt][st] = (f32x4)(0.f);
    for (int dstep = 0; dstep < 8; ++dstep) {
      bf16x8 a0 = *(const bf16x8*)&ze_s[(c) * 264 + dstep * 32 + q * 8];
      bf16x8 a1 = *(const bf16x8*)&ze_s[(16 + c) * 264 + dstep * 32 + q * 8];
#pragma unroll
      for (int st = 0; st < 4; ++st) {
        bf16x8 bB = *(const bf16x8*)&bbf[((size_t)(k * Ss + w * 64 + st * 16 + c)) * 256 +
                                         dstep * 32 + q * 8];
        acc1[0][st] = __builtin_amdgcn_mfma_f32_16x16x32_bf16(a0, bB, acc1[0][st], 0, 0, 0);
        acc1[1][st] = __builtin_amdgcn_mfma_f32_16x16x32_bf16(a1, bB, acc1[1][st], 0, 0, 0);
      }
    }

    // ---- scores + gumbel in C-layout registers
    float b2v[4];
#pragma unroll
    for (int st = 0; st < 4; ++st) b2v[st] = b2p[k * Ss + w * 64 + st * 16 + c];
    float mx[2][4], sm[2][4];
#pragma unroll
    for (int rt = 0; rt < 2; ++rt)
#pragma unroll
      for (int reg = 0; reg < 4; ++reg) mx[rt][reg] = -3.0e38f;
#pragma unroll
    for (int rt = 0; rt < 2; ++rt)
#pragma unroll
      for (int st = 0; st < 4; ++st)
#pragma unroll
        for (int reg = 0; reg < 4; ++reg) {
          int row = n0 + rt * 16 + q * 4 + reg;
          uint32_t gi = ((uint32_t)(b * Nn + row) * (uint32_t)Kk + (uint32_t)k) * (uint32_t)Ss +
                        (uint32_t)(w * 64 + st * 16 + c);
          float g = jax_gumbel(KG2, gi, 0u);
          float v = ((2.f * acc1[rt][st][reg] - b2v[st]) * pq + g) * 2.f;
          acc1[rt][st][reg] = v;
          mx[rt][reg] = fmaxf(mx[rt][reg], v);
        }
#pragma unroll
    for (int m = 1; m < 16; m <<= 1)
#pragma unroll
      for (int rt = 0; rt < 2; ++rt)
#pragma unroll
        for (int reg = 0; reg < 4; ++reg)
          mx[rt][reg] = fmaxf(mx[rt][reg], __shfl_xor(mx[rt][reg], m));
#pragma unroll
    for (int rt = 0; rt < 2; ++rt)
#pragma unroll
      for (int reg = 0; reg < 4; ++reg) sm[rt][reg] = 0.f;
#pragma unroll
    for (int rt = 0; rt < 2; ++rt)
#pragma unroll
      for (int st = 0; st < 4; ++st)
#pragma unroll
        for (int reg = 0; reg < 4; ++reg) {
          float e = __expf(acc1[rt][st][reg] - mx[rt][reg]);
          acc1[rt][st][reg] = e;
          sm[rt][reg] += e;
        }
#pragma unroll
    for (int m = 1; m < 16; m <<= 1)
#pragma unroll
      for (int rt = 0; rt < 2; ++rt)
#pragma unroll
        for (int reg = 0; reg < 4; ++reg) sm[rt][reg] += __shfl_xor(sm[rt][reg], m);
    if (c == 0) {
#pragma unroll
      for (int rt = 0; rt < 2; ++rt)
#pragma unroll
        for (int reg = 0; reg < 4; ++reg) {
          int rl = rt * 16 + q * 4 + reg;
          redms[rl][w] = make_float2(mx[rt][reg], sm[rt][reg]);
        }
    }
    __syncthreads();  // barA: red array complete; also orders enc writes after
                      // all GEMM2(k-1) reads.

    // ---- distributed combine: every lane computes M,T for its own 8 rows,
    //      then writes normalized enc (bf16, A-layout source)
    const float cpv = cpk[k];
#pragma unroll
    for (int rt = 0; rt < 2; ++rt)
#pragma unroll
      for (int reg = 0; reg < 4; ++reg) {
        int rl = rt * 16 + q * 4 + reg;
        float M = mx[rt][reg];
#pragma unroll
        for (int w2 = 0; w2 < 8; ++w2) M = fmaxf(M, redms[rl][w2].x);
        float T = 0.f;
#pragma unroll
        for (int w2 = 0; w2 < 8; ++w2)
          T = fmaf(redms[rl][w2].y, __expf(redms[rl][w2].x - M), T);
        float scale = cpv * __expf(mx[rt][reg] - M) * __builtin_amdgcn_rcpf(T);
#pragma unroll
        for (int st = 0; st < 4; ++st)
          enc_s[rl * 520 + w * 64 + st * 16 + c] = f2bf(acc1[rt][st][reg] * scale);
      }
    __syncthreads();  // barB: enc complete for GEMM2

    // ---- GEMM2: zq += enc . bookT[k]   (no tail barrier: next k's red/enc
    //      writes are ordered behind barA(k+1)/barB(k+1))
    for (int ss = 0; ss < 16; ++ss) {
      bf16x8 a0 = *(const bf16x8*)&enc_s[(c) * 520 + ss * 32 + q * 8];
      bf16x8 a1 = *(const bf16x8*)&enc_s[(16 + c) * 520 + ss * 32 + q * 8];
#pragma unroll
      for (int dt = 0; dt < 2; ++dt) {
        bf16x8 bB = *(const bf16x8*)&btf[((size_t)(k * 256 + w * 32 + dt * 16 + c)) * 512 +
                                         ss * 32 + q * 8];
        acc2[0][dt] = __builtin_amdgcn_mfma_f32_16x16x32_bf16(a0, bB, acc2[0][dt], 0, 0, 0);
        acc2[1][dt] = __builtin_amdgcn_mfma_f32_16x16x32_bf16(a1, bB, acc2[1][dt], 0, 0, 0);
      }
    }
  }

  // ---- epilogue: C-layout -> global zq
#pragma unroll
  for (int rt = 0; rt < 2; ++rt)
#pragma unroll
    for (int dt = 0; dt < 2; ++dt)
#pragma unroll
      for (int reg = 0; reg < 4; ++reg) {
        int row = n0 + rt * 16 + q * 4 + reg;
        int d = w * 32 + dt * 16 + c;
        out[(size_t)(b * Nn + row) * Dd + d] = acc2[rt][dt][reg];
      }
}

}  // namespace

extern "C" void kernel_launch(void* const* d_in, const int* in_sizes, int n_in,
                              void* d_out, int out_size, void* d_ws, size_t ws_size,
                              hipStream_t stream) {
  (void)in_sizes; (void)n_in; (void)out_size; (void)ws_size;
  const float* ze = (const float*)d_in[0];
  const float* c_logits = (const float*)d_in[1];
  const float* books = (const float*)d_in[2];
  const float* lpq = (const float*)d_in[3];
  const float* lpq_cls = (const float*)d_in[4];
  float* out = (float*)d_out;
  float* ws = (float*)d_ws;

  hipLaunchKernelGGL(cprobs_kernel, dim3(1), dim3(256), 0, stream,
                     c_logits, lpq, lpq_cls, ws, out);
  hipLaunchKernelGGL(norms_kernel, dim3(Kk * Ss / 4), dim3(256), 0, stream, books, ws);
  hipLaunchKernelGGL(prep_kernel, dim3(Kk * 32), dim3(256), 0, stream, books, ws);
  hipLaunchKernelGGL(wbooks_kernel, dim3(Bsz * Ss), dim3(256), 0, stream, books, ws);
  hipLaunchKernelGGL(mlogits_kernel, dim3(Bsz * (Nn / 32)), dim3(512), 0, stream,
                     ze, lpq, ws, out);
  hipLaunchKernelGGL(zq_kernel, dim3(Bsz * (Nn / 32)), dim3(512), 0, stream,
                     ze, lpq, ws, out);
}

// Round 7
// 724.023 us; speedup vs baseline: 2.0343x; 1.0002x over previous
//
#include <hip/hip_runtime.h>
#include <cstdint>
#include <cstddef>

#define JAX_PARTITIONABLE 1

namespace {

constexpr int Bsz = 16, Nn = 1024, Dd = 256, Kk = 16, Ss = 512;
constexpr uint32_t BN = (uint32_t)Bsz * Nn;                    // 16384
constexpr int ZQ_SIZE = Bsz * Nn * Dd;                          // 4194304
constexpr int PQ_OFF = ZQ_SIZE;
constexpr int PROB_OFF = ZQ_SIZE + 1;
constexpr int BNS = Bsz * Nn * Ss;                              // 8388608
constexpr int LP_OFF = PROB_OFF + BNS;

// workspace layout (float offsets)
constexpr int WS_CP = 0;                           // 256
constexpr int WS_B2 = 256;                         // K*S = 8192
constexpr int WS_WB2 = WS_B2 + Kk * Ss;            // B*S = 8192
constexpr int WS_WBF = WS_WB2 + Bsz * Ss;          // wbooks bf16 [b][s][d]: 2M shorts
constexpr int WS_BBF = WS_WBF + Bsz * Ss * Dd;     // books bf16
constexpr int WS_BTF = WS_BBF + (Kk * Ss * Dd) / 2; // bookT bf16 [k][d][s]
// total ~4.2M floats ~ 16.9 MB

constexpr float LOG2E = 1.4426950408889634f;

typedef __attribute__((ext_vector_type(8))) short bf16x8;
typedef __attribute__((ext_vector_type(4))) short short4v;
typedef __attribute__((ext_vector_type(4))) float f32x4;

// hw transcendental wrappers (v_exp_f32 / v_log_f32 are base-2)
__device__ __forceinline__ float hw_exp2(float x) { return __builtin_amdgcn_exp2f(x); }
__device__ __forceinline__ float hw_log2(float x) { return __builtin_amdgcn_logf(x); }

struct KP { uint32_t a, b; };

__host__ __device__ constexpr KP tf2x32(uint32_t k0, uint32_t k1,
                                        uint32_t x0, uint32_t x1) {
  uint32_t ks[3] = {k0, k1, k0 ^ k1 ^ 0x1BD11BDAu};
  const int rot[2][4] = {{13, 15, 26, 6}, {17, 29, 16, 24}};
  x0 += ks[0];
  x1 += ks[1];
#pragma unroll
  for (int i = 0; i < 5; ++i) {
#pragma unroll
    for (int j = 0; j < 4; ++j) {
      int r = rot[i & 1][j];
      x0 += x1;
      x1 = (x1 << r) | (x1 >> (32 - r));
      x1 ^= x0;
    }
    x0 += ks[(i + 1) % 3];
    x1 += ks[(i + 2) % 3] + (uint32_t)(i + 1);
  }
  return {x0, x1};
}

#if JAX_PARTITIONABLE
constexpr KP KG1 = tf2x32(0u, 42u, 0u, 0u);
constexpr KP KG2 = tf2x32(0u, 42u, 0u, 1u);
#else
constexpr KP KH0 = tf2x32(0u, 42u, 0u, 2u);
constexpr KP KH1 = tf2x32(0u, 42u, 1u, 3u);
constexpr KP KG1 = {KH0.a, KH1.a};
constexpr KP KG2 = {KH0.b, KH1.b};
#endif

__device__ __forceinline__ float jax_gumbel(KP key, uint32_t idx, uint32_t half) {
#if JAX_PARTITIONABLE
  (void)half;
  KP h = tf2x32(key.a, key.b, 0u, idx);
  uint32_t bits = h.a ^ h.b;
#else
  uint32_t lo = idx < half ? idx : idx - half;
  KP h = tf2x32(key.a, key.b, lo, lo + half);
  uint32_t bits = idx < half ? h.a : h.b;
#endif
  float u = __uint_as_float((bits >> 9) | 0x3F800000u) - 1.0f;
  return -__logf(-__logf(u + 1e-10f) + 1e-10f);
}

// gumbel scaled into the exp2 softmax domain: returns g * 2 * log2e
// (= -2*log2(y), exact same quantity with one fewer rounding).
__device__ __forceinline__ float jax_gumbel_w2(KP key, uint32_t idx) {
  KP h = tf2x32(key.a, key.b, 0u, idx);
  uint32_t bits = h.a ^ h.b;
  float u = __uint_as_float((bits >> 9) | 0x3F800000u) - 1.0f;
  float y = -__logf(u + 1e-10f) + 1e-10f;
  return -2.0f * hw_log2(y);
}

__device__ __forceinline__ float prec_q(const float* p) {
  return 0.5f / fmaxf(1.0f + expf(p[0]), 1e-10f);
}

__device__ __forceinline__ short f2bf(float x) {  // RNE f32->bf16
  uint32_t u = __float_as_uint(x);
  uint32_t r = (u + 0x7FFFu + ((u >> 16) & 1u)) >> 16;
  return (short)r;
}

// ---------------- K1: c_probs (B,K) + precision_q ----------------
__global__ void __launch_bounds__(256) cprobs_kernel(
    const float* __restrict__ c_logits, const float* __restrict__ lpq,
    const float* __restrict__ lpq_cls, float* __restrict__ ws,
    float* __restrict__ out) {
  __shared__ float sl[256];
  const int t = threadIdx.x;
  const float pqc = prec_q(lpq_cls);
  float g = jax_gumbel(KG1, (uint32_t)t, 128u);
  sl[t] = (c_logits[t] * pqc + g) * 2.0f;  // /TEMP, TEMP=0.5
  __syncthreads();
  const int b = t >> 4;
  float m = -3.0e38f;
  for (int j = 0; j < 16; ++j) m = fmaxf(m, sl[b * 16 + j]);
  float sum = 0.f;
  for (int j = 0; j < 16; ++j) sum += expf(sl[b * 16 + j] - m);
  ws[WS_CP + t] = expf(sl[t] - m) / sum;
  if (t == 0) out[PQ_OFF] = prec_q(lpq);
}

// ---------------- K2: b2 (K*S) ----------------
__global__ void __launch_bounds__(256) norms_kernel(
    const float* __restrict__ books, float* __restrict__ ws) {
  const int row = blockIdx.x * 4 + (threadIdx.x >> 6);
  const int lane = threadIdx.x & 63;
  float4 v = ((const float4*)(books + (size_t)row * Dd))[lane];
  float s = v.x * v.x + v.y * v.y + v.z * v.z + v.w * v.w;
#pragma unroll
  for (int d = 1; d < 64; d <<= 1) s += __shfl_xor(s, d);
  if (lane == 0) ws[WS_B2 + row] = s;
}

// ---------------- K3: books -> bf16 + transposed bf16 ----------------
__global__ void __launch_bounds__(256) prep_kernel(
    const float* __restrict__ books, float* __restrict__ ws) {
  __shared__ short tile[16 * 256];
  const int k = blockIdx.x >> 5;
  const int s0 = (blockIdx.x & 31) << 4;
  short* bbf = (short*)(ws + WS_BBF);
  short* btf = (short*)(ws + WS_BTF);
  const int t = threadIdx.x;
#pragma unroll
  for (int i = 0; i < 4; ++i) {
    int idx = t + 256 * i;  // 0..1023
    int r = idx >> 6, dq = idx & 63;
    float4 v = ((const float4*)books)[(size_t)(k * Ss + s0 + r) * 64 + dq];
    short4v h = {f2bf(v.x), f2bf(v.y), f2bf(v.z), f2bf(v.w)};
    *(short4v*)&bbf[(size_t)(k * Ss + s0 + r) * 256 + dq * 4] = h;
    *(short4v*)&tile[r * 256 + dq * 4] = h;
  }
  __syncthreads();
  const int d = t;  // 0..255
  short vals[16];
#pragma unroll
  for (int r = 0; r < 16; ++r) vals[r] = tile[r * 256 + d];
  bf16x8 lo, hi;
#pragma unroll
  for (int r = 0; r < 8; ++r) { lo[r] = vals[r]; hi[r] = vals[r + 8]; }
  size_t base = ((size_t)(k * 256 + d)) * 512 + s0;
  *(bf16x8*)&btf[base] = lo;
  *(bf16x8*)&btf[base + 8] = hi;
}

// ---------------- K4: wbooks bf16 (B,S,D) and wb2 (B,S) ----------------
__global__ void __launch_bounds__(256) wbooks_kernel(
    const float* __restrict__ books, float* __restrict__ ws) {
  const int bs = blockIdx.x;           // b*512 + s
  const int b = bs >> 9, s = bs & 511;
  const int d = threadIdx.x;
  const float* cp = ws + WS_CP + b * 16;
  float acc = 0.f;
#pragma unroll
  for (int k = 0; k < 16; ++k)
    acc = fmaf(cp[k], books[((size_t)(k * Ss + s)) * Dd + d], acc);
  short* wbf = (short*)(ws + WS_WBF);
  wbf[((size_t)(b * Ss + s)) * Dd + d] = f2bf(acc);
  if (d == 0) {
    float a2 = 0.f;
#pragma unroll
    for (int k = 0; k < 16; ++k) a2 = fmaf(cp[k], ws[WS_B2 + k * Ss + s], a2);
    ws[WS_WB2 + b * Ss + s] = a2;
  }
}

// ---------------- K5+K6 merged: blockIdx<512 -> zq, else -> mlogits ----------------
// zq (round-2 verified structure, exp2-domain softmax): 32-row n-tile, 8 waves,
// VGPR 64 + AGPR 48 = 112 unified -> 4 waves/SIMD (rounds 1/4: tighter caps spill).
// Softmax computed in w = v*log2e domain: score transform fma-folded
// (w = fma(acc, 4*pq*log2e, -2*pq*log2e*b2) + gw, gw = -2*log2(y)), all
// exp() replaced by single-instruction v_exp_f32 (base-2). Same softmax value.
// mlogits: MFMA logits vs wbooks-bf16 + cross-wave softmax -> prob/log_prob.
// Merging absorbs mlogits' serial dispatch time under the zq long-pole blocks.
__global__ void __launch_bounds__(512, 4) fused_kernel(
    const float* __restrict__ ze, const float* __restrict__ lpq,
    const float* __restrict__ ws, float* __restrict__ out) {
  __shared__ short ze_s[32 * 264];   // bf16, row stride 264 (bank-balanced)
  __shared__ short enc_s[32 * 520];  // bf16, row stride 520 (zq only)
  __shared__ float2 redms[32][9];    // [row][wave] = (max, sum), padded
  __shared__ float cpk[16];

  const int t = threadIdx.x;
  const int w = t >> 6, lane = t & 63, c = lane & 15, q = lane >> 4;
  const float pq = prec_q(lpq);

  if (blockIdx.x < 512) {
    // ================= zq path =================
    const int b = blockIdx.x >> 5;
    const int n0 = (blockIdx.x & 31) << 5;
    const short* bbf = (const short*)(ws + WS_BBF);
    const short* btf = (const short*)(ws + WS_BTF);
    const float* b2p = ws + WS_B2;
    const float ca = 4.f * pq * LOG2E;          // score->w-domain scale
    const float cbs = -2.f * pq * LOG2E;        // b2 fold

    if (t < 16) cpk[t] = ws[WS_CP + b * 16 + t];
#pragma unroll
    for (int i = 0; i < 4; ++i) {
      int idx = t + 512 * i;  // 0..2047
      int r = idx >> 6, dq = idx & 63;
      float4 v = ((const float4*)ze)[(size_t)(b * Nn + n0 + r) * 64 + dq];
      short4v h = {f2bf(v.x), f2bf(v.y), f2bf(v.z), f2bf(v.w)};
      *(short4v*)&ze_s[r * 264 + dq * 4] = h;
    }
    __syncthreads();

    f32x4 acc2[2][2];
#pragma unroll
    for (int rt = 0; rt < 2; ++rt)
#pragma unroll
      for (int dt = 0; dt < 2; ++dt) acc2[rt][dt] = (f32x4)(0.f);

    for (int k = 0; k < 16; ++k) {
      // ---- GEMM1: scores = ze . books[k]^T
      f32x4 acc1[2][4];
#pragma unroll
      for (int rt = 0; rt < 2; ++rt)
#pragma unroll
        for (int st = 0; st < 4; ++st) acc1[rt][st] = (f32x4)(0.f);
      for (int dstep = 0; dstep < 8; ++dstep) {
        bf16x8 a0 = *(const bf16x8*)&ze_s[(c) * 264 + dstep * 32 + q * 8];
        bf16x8 a1 = *(const bf16x8*)&ze_s[(16 + c) * 264 + dstep * 32 + q * 8];
#pragma unroll
        for (int st = 0; st < 4; ++st) {
          bf16x8 bB = *(const bf16x8*)&bbf[((size_t)(k * Ss + w * 64 + st * 16 + c)) * 256 +
                                           dstep * 32 + q * 8];
          acc1[0][st] = __builtin_amdgcn_mfma_f32_16x16x32_bf16(a0, bB, acc1[0][st], 0, 0, 0);
          acc1[1][st] = __builtin_amdgcn_mfma_f32_16x16x32_bf16(a1, bB, acc1[1][st], 0, 0, 0);
        }
      }

      // ---- w-domain scores + gumbel in C-layout registers
      float cb[4];
#pragma unroll
      for (int st = 0; st < 4; ++st) cb[st] = cbs * b2p[k * Ss + w * 64 + st * 16 + c];
      float mx[2][4], sm[2][4];
#pragma unroll
      for (int rt = 0; rt < 2; ++rt)
#pragma unroll
        for (int reg = 0; reg < 4; ++reg) mx[rt][reg] = -3.0e38f;
#pragma unroll
      for (int rt = 0; rt < 2; ++rt)
#pragma unroll
        for (int st = 0; st < 4; ++st)
#pragma unroll
          for (int reg = 0; reg < 4; ++reg) {
            int row = n0 + rt * 16 + q * 4 + reg;
            uint32_t gi = ((uint32_t)(b * Nn + row) * (uint32_t)Kk + (uint32_t)k) * (uint32_t)Ss +
                          (uint32_t)(w * 64 + st * 16 + c);
            float gw = jax_gumbel_w2(KG2, gi);
            float v = fmaf(acc1[rt][st][reg], ca, cb[st]) + gw;
            acc1[rt][st][reg] = v;
            mx[rt][reg] = fmaxf(mx[rt][reg], v);
          }
#pragma unroll
      for (int m = 1; m < 16; m <<= 1)
#pragma unroll
        for (int rt = 0; rt < 2; ++rt)
#pragma unroll
          for (int reg = 0; reg < 4; ++reg)
            mx[rt][reg] = fmaxf(mx[rt][reg], __shfl_xor(mx[rt][reg], m));
#pragma unroll
      for (int rt = 0; rt < 2; ++rt)
#pragma unroll
        for (int reg = 0; reg < 4; ++reg) sm[rt][reg] = 0.f;
#pragma unroll
      for (int rt = 0; rt < 2; ++rt)
#pragma unroll
        for (int st = 0; st < 4; ++st)
#pragma unroll
          for (int reg = 0; reg < 4; ++reg) {
            float e = hw_exp2(acc1[rt][st][reg] - mx[rt][reg]);
            acc1[rt][st][reg] = e;
            sm[rt][reg] += e;
          }
#pragma unroll
      for (int m = 1; m < 16; m <<= 1)
#pragma unroll
        for (int rt = 0; rt < 2; ++rt)
#pragma unroll
          for (int reg = 0; reg < 4; ++reg) sm[rt][reg] += __shfl_xor(sm[rt][reg], m);
      if (c == 0) {
#pragma unroll
        for (int rt = 0; rt < 2; ++rt)
#pragma unroll
          for (int reg = 0; reg < 4; ++reg) {
            int rl = rt * 16 + q * 4 + reg;
            redms[rl][w] = make_float2(mx[rt][reg], sm[rt][reg]);
          }
      }
      __syncthreads();  // barA: red array complete; also orders enc writes after
                        // all GEMM2(k-1) reads.

      // ---- distributed combine + normalized enc (bf16, A-layout source)
      const float cpv = cpk[k];
#pragma unroll
      for (int rt = 0; rt < 2; ++rt)
#pragma unroll
        for (int reg = 0; reg < 4; ++reg) {
          int rl = rt * 16 + q * 4 + reg;
          float M = mx[rt][reg];
#pragma unroll
          for (int w2 = 0; w2 < 8; ++w2) M = fmaxf(M, redms[rl][w2].x);
          float T = 0.f;
#pragma unroll
          for (int w2 = 0; w2 < 8; ++w2)
            T = fmaf(redms[rl][w2].y, hw_exp2(redms[rl][w2].x - M), T);
          float scale = cpv * hw_exp2(mx[rt][reg] - M) * __builtin_amdgcn_rcpf(T);
#pragma unroll
          for (int st = 0; st < 4; ++st)
            enc_s[rl * 520 + w * 64 + st * 16 + c] = f2bf(acc1[rt][st][reg] * scale);
        }
      __syncthreads();  // barB: enc complete for GEMM2

      // ---- GEMM2: zq += enc . bookT[k]
      for (int ss = 0; ss < 16; ++ss) {
        bf16x8 a0 = *(const bf16x8*)&enc_s[(c) * 520 + ss * 32 + q * 8];
        bf16x8 a1 = *(const bf16x8*)&enc_s[(16 + c) * 520 + ss * 32 + q * 8];
#pragma unroll
        for (int dt = 0; dt < 2; ++dt) {
          bf16x8 bB = *(const bf16x8*)&btf[((size_t)(k * 256 + w * 32 + dt * 16 + c)) * 512 +
                                           ss * 32 + q * 8];
          acc2[0][dt] = __builtin_amdgcn_mfma_f32_16x16x32_bf16(a0, bB, acc2[0][dt], 0, 0, 0);
          acc2[1][dt] = __builtin_amdgcn_mfma_f32_16x16x32_bf16(a1, bB, acc2[1][dt], 0, 0, 0);
        }
      }
    }

    // ---- epilogue: C-layout -> global zq
#pragma unroll
    for (int rt = 0; rt < 2; ++rt)
#pragma unroll
      for (int dt = 0; dt < 2; ++dt)
#pragma unroll
        for (int reg = 0; reg < 4; ++reg) {
          int row = n0 + rt * 16 + q * 4 + reg;
          int d = w * 32 + dt * 16 + c;
          out[(size_t)(b * Nn + row) * Dd + d] = acc2[rt][dt][reg];
        }
  } else {
    // ================= mlogits path =================
    const int mbid = blockIdx.x - 512;
    const int b = mbid >> 5;
    const int n0 = (mbid & 31) << 5;
    const short* wbf = (const short*)(ws + WS_WBF);
    const float* wb2 = ws + WS_WB2;

#pragma unroll
    for (int i = 0; i < 4; ++i) {
      int idx = t + 512 * i;  // 0..2047
      int r = idx >> 6, dq = idx & 63;
      float4 v = ((const float4*)ze)[(size_t)(b * Nn + n0 + r) * 64 + dq];
      short4v h = {f2bf(v.x), f2bf(v.y), f2bf(v.z), f2bf(v.w)};
      *(short4v*)&ze_s[r * 264 + dq * 4] = h;
    }
    __syncthreads();

    f32x4 acc1[2][4];
#pragma unroll
    for (int rt = 0; rt < 2; ++rt)
#pragma unroll
      for (int st = 0; st < 4; ++st) acc1[rt][st] = (f32x4)(0.f);
    for (int dstep = 0; dstep < 8; ++dstep) {
      bf16x8 a0 = *(const bf16x8*)&ze_s[(c) * 264 + dstep * 32 + q * 8];
      bf16x8 a1 = *(const bf16x8*)&ze_s[(16 + c) * 264 + dstep * 32 + q * 8];
#pragma unroll
      for (int st = 0; st < 4; ++st) {
        bf16x8 bB = *(const bf16x8*)&wbf[((size_t)(b * Ss + w * 64 + st * 16 + c)) * 256 +
                                         dstep * 32 + q * 8];
        acc1[0][st] = __builtin_amdgcn_mfma_f32_16x16x32_bf16(a0, bB, acc1[0][st], 0, 0, 0);
        acc1[1][st] = __builtin_amdgcn_mfma_f32_16x16x32_bf16(a1, bB, acc1[1][st], 0, 0, 0);
      }
    }

    float mx[2][4], sm[2][4];
#pragma unroll
    for (int rt = 0; rt < 2; ++rt)
#pragma unroll
      for (int reg = 0; reg < 4; ++reg) mx[rt][reg] = -3.0e38f;
#pragma unroll
    for (int st = 0; st < 4; ++st) {
      const float wb2v = wb2[b * Ss + w * 64 + st * 16 + c];
#pragma unroll
      for (int rt = 0; rt < 2; ++rt)
#pragma unroll
        for (int reg = 0; reg < 4; ++reg) {
          float v = (2.f * acc1[rt][st][reg] - wb2v) * pq;
          acc1[rt][st][reg] = v;
          mx[rt][reg] = fmaxf(mx[rt][reg], v);
        }
    }
#pragma unroll
    for (int m = 1; m < 16; m <<= 1)
#pragma unroll
      for (int rt = 0; rt < 2; ++rt)
#pragma unroll
        for (int reg = 0; reg < 4; ++reg)
          mx[rt][reg] = fmaxf(mx[rt][reg], __shfl_xor(mx[rt][reg], m));
#pragma unroll
    for (int rt = 0; rt < 2; ++rt)
#pragma unroll
      for (int reg = 0; reg < 4; ++reg) sm[rt][reg] = 0.f;
#pragma unroll
    for (int st = 0; st < 4; ++st)
#pragma unroll
      for (int rt = 0; rt < 2; ++rt)
#pragma unroll
        for (int reg = 0; reg < 4; ++reg)
          sm[rt][reg] += __expf(acc1[rt][st][reg] - mx[rt][reg]);
#pragma unroll
    for (int m = 1; m < 16; m <<= 1)
#pragma unroll
      for (int rt = 0; rt < 2; ++rt)
#pragma unroll
        for (int reg = 0; reg < 4; ++reg) sm[rt][reg] += __shfl_xor(sm[rt][reg], m);
    if (c == 0) {
#pragma unroll
      for (int rt = 0; rt < 2; ++rt)
#pragma unroll
        for (int reg = 0; reg < 4; ++reg)
          redms[rt * 16 + q * 4 + reg][w] = make_float2(mx[rt][reg], sm[rt][reg]);
    }
    __syncthreads();

#pragma unroll
    for (int rt = 0; rt < 2; ++rt)
#pragma unroll
      for (int reg = 0; reg < 4; ++reg) {
        int rl = rt * 16 + q * 4 + reg;
        float M = mx[rt][reg];
#pragma unroll
        for (int w2 = 0; w2 < 8; ++w2) M = fmaxf(M, redms[rl][w2].x);
        float T = 0.f;
#pragma unroll
        for (int w2 = 0; w2 < 8; ++w2)
          T = fmaf(redms[rl][w2].y, __expf(redms[rl][w2].x - M), T);
        const float invT = __builtin_amdgcn_rcpf(T);
        const float lT = __logf(T);
        const size_t base = (size_t)(b * Nn + n0 + rl) * Ss;
#pragma unroll
        for (int st = 0; st < 4; ++st) {
          int s = w * 64 + st * 16 + c;
          float v = acc1[rt][st][reg] - M;
          out[PROB_OFF + base + s] = __expf(v) * invT;
          out[LP_OFF + base + s] = v - lT;
        }
      }
  }
}

}  // namespace

extern "C" void kernel_launch(void* const* d_in, const int* in_sizes, int n_in,
                              void* d_out, int out_size, void* d_ws, size_t ws_size,
                              hipStream_t stream) {
  (void)in_sizes; (void)n_in; (void)out_size; (void)ws_size;
  const float* ze = (const float*)d_in[0];
  const float* c_logits = (const float*)d_in[1];
  const float* books = (const float*)d_in[2];
  const float* lpq = (const float*)d_in[3];
  const float* lpq_cls = (const float*)d_in[4];
  float* out = (float*)d_out;
  float* ws = (float*)d_ws;

  hipLaunchKernelGGL(cprobs_kernel, dim3(1), dim3(256), 0, stream,
                     c_logits, lpq, lpq_cls, ws, out);
  hipLaunchKernelGGL(norms_kernel, dim3(Kk * Ss / 4), dim3(256), 0, stream, books, ws);
  hipLaunchKernelGGL(prep_kernel, dim3(Kk * 32), dim3(256), 0, stream, books, ws);
  hipLaunchKernelGGL(wbooks_kernel, dim3(Bsz * Ss), dim3(256), 0, stream, books, ws);
  hipLaunchKernelGGL(fused_kernel, dim3(1024), dim3(512), 0, stream,
                     ze, lpq, ws, out);
}